// Round 4
// baseline (469.404 us; speedup 1.0000x reference)
//
#include <hip/hip_runtime.h>
#include <math.h>

constexpr int KK = 2;
constexpr int HH = 4;
constexpr int NN = 4096;
constexpr int DD = 64;
constexpr int OO = 64;
constexpr int NU = 4000;
constexpr int CC = 2;
constexpr int JSPLIT = 4;
constexpr int JCHUNK = NN / JSPLIT;  // 1024
constexpr float LOG2E = 1.44269504088896340736f;

typedef float vf4 __attribute__((ext_vector_type(4)));  // native vec for builtins

__device__ __forceinline__ float fexp2(float x) {
#if __has_builtin(__builtin_amdgcn_exp2f)
  return __builtin_amdgcn_exp2f(x);
#else
  return exp2f(x);
#endif
}
__device__ __forceinline__ float frcp(float x) {
#if __has_builtin(__builtin_amdgcn_rcpf)
  return __builtin_amdgcn_rcpf(x);
#else
  return 1.0f / x;
#endif
}
__device__ __forceinline__ float ftanh(float x) {
  float e = fexp2(x * (2.0f * LOG2E));
  return 1.0f - 2.0f * frcp(e + 1.0f);
}

// ---------------------------------------------------------------------------
// Phase 1: per (k,h): hp = h @ w (4096x64 @ 64x64); per node j:
//   src_s[kh][j] = (tanh(hp_j).a_src)*log2e
//   att_d [kh][j] = (tanh(hp_j).a_dst)*log2e
//   att_g0[kh][j] = hp_j . fc_w[0, k*O:], att_g1 likewise  (SoA planes!)
// grid (64, K*H), block 256. Thread = 4 rows x 4 o outer-product tile.
// ---------------------------------------------------------------------------
__global__ __launch_bounds__(256) void gat_phase1(
    const float* __restrict__ hsrc, const float* __restrict__ w,
    const float* __restrict__ a_src, const float* __restrict__ a_dst,
    const float* __restrict__ fc_w,
    float* __restrict__ src_s, float* __restrict__ att_d,
    float* __restrict__ att_g0, float* __restrict__ att_g1) {
  const int kh = blockIdx.y;  // 0..7
  const int k = kh >> 2;
  const int i0 = blockIdx.x * 64;
  const int tid = threadIdx.x;

  __shared__ float h_s[DD][68];
  __shared__ float w_s[DD][OO];

  {
    const float4* wp = (const float4*)(w + (size_t)kh * DD * OO);
    float4* ws4 = (float4*)w_s;
    for (int t = tid; t < DD * OO / 4; t += 256) ws4[t] = wp[t];
  }
  for (int t = tid; t < 1024; t += 256) {
    const int row = t >> 4;
    const int f4 = (t & 15) * 4;
    float4 v = *(const float4*)(hsrc + (size_t)(i0 + row) * DD + f4);
    h_s[f4 + 0][row] = v.x;
    h_s[f4 + 1][row] = v.y;
    h_s[f4 + 2][row] = v.z;
    h_s[f4 + 3][row] = v.w;
  }
  __syncthreads();

  const int og = tid & 15;
  const int rg = tid >> 4;
  const int o0 = og * 4;
  const int r0 = rg * 4;

  float hp[4][4];
#pragma unroll
  for (int j = 0; j < 4; ++j)
#pragma unroll
    for (int u = 0; u < 4; ++u) hp[j][u] = 0.0f;

#pragma unroll 8
  for (int f = 0; f < DD; ++f) {
    float4 hv = *(const float4*)&h_s[f][r0];
    float4 wv = *(const float4*)&w_s[f][o0];
    hp[0][0] = fmaf(hv.x, wv.x, hp[0][0]);
    hp[0][1] = fmaf(hv.x, wv.y, hp[0][1]);
    hp[0][2] = fmaf(hv.x, wv.z, hp[0][2]);
    hp[0][3] = fmaf(hv.x, wv.w, hp[0][3]);
    hp[1][0] = fmaf(hv.y, wv.x, hp[1][0]);
    hp[1][1] = fmaf(hv.y, wv.y, hp[1][1]);
    hp[1][2] = fmaf(hv.y, wv.z, hp[1][2]);
    hp[1][3] = fmaf(hv.y, wv.w, hp[1][3]);
    hp[2][0] = fmaf(hv.z, wv.x, hp[2][0]);
    hp[2][1] = fmaf(hv.z, wv.y, hp[2][1]);
    hp[2][2] = fmaf(hv.z, wv.z, hp[2][2]);
    hp[2][3] = fmaf(hv.z, wv.w, hp[2][3]);
    hp[3][0] = fmaf(hv.w, wv.x, hp[3][0]);
    hp[3][1] = fmaf(hv.w, wv.y, hp[3][1]);
    hp[3][2] = fmaf(hv.w, wv.z, hp[3][2]);
    hp[3][3] = fmaf(hv.w, wv.w, hp[3][3]);
  }

  float as[4], ad[4], f0[4], f1[4];
#pragma unroll
  for (int u = 0; u < 4; ++u) {
    as[u] = a_src[kh * OO + o0 + u];
    ad[u] = a_dst[kh * OO + o0 + u];
    f0[u] = fc_w[0 * (KK * OO) + k * OO + o0 + u];
    f1[u] = fc_w[1 * (KK * OO) + k * OO + o0 + u];
  }

#pragma unroll
  for (int j = 0; j < 4; ++j) {
    float sp = 0.0f, dp = 0.0f, g0 = 0.0f, g1 = 0.0f;
#pragma unroll
    for (int u = 0; u < 4; ++u) {
      float v = hp[j][u];
      float t = ftanh(v);
      sp = fmaf(t, as[u], sp);
      dp = fmaf(t, ad[u], dp);
      g0 = fmaf(v, f0[u], g0);
      g1 = fmaf(v, f1[u], g1);
    }
#pragma unroll
    for (int off = 1; off < 16; off <<= 1) {
      sp += __shfl_xor(sp, off, 64);
      dp += __shfl_xor(dp, off, 64);
      g0 += __shfl_xor(g0, off, 64);
      g1 += __shfl_xor(g1, off, 64);
    }
    if (og == 0) {
      const int i = i0 + r0 + j;
      src_s[kh * NN + i] = sp * LOG2E;
      att_d[kh * NN + i] = dp * LOG2E;
      att_g0[kh * NN + i] = g0;
      att_g1[kh * NN + i] = g1;
    }
  }
}

// ---------------------------------------------------------------------------
// Phase 2: partial softmax sums over a 1024-j chunk, 8 rows per wave.
// grid (NU/8, K*JSPLIT), block 64 (one wave). SoA att planes -> every load
// is a dense b128 (1KB/wave = 16 cache lines per instruction).
//   p = adj * exp2(leaky(src'+dst')); l += p; a_c += p*g_c
// Butterfly reduce 96 sums; lane0 writes partials (no division).
// ---------------------------------------------------------------------------
__global__ __launch_bounds__(64, 3) void gat_phase2(
    const float* __restrict__ adj, const float* __restrict__ src_s,
    const float* __restrict__ att_d, const float* __restrict__ att_g0,
    const float* __restrict__ att_g1, float* __restrict__ P) {
  const int k = blockIdx.y >> 2;
  const int chunk = blockIdx.y & 3;
  const int r0 = blockIdx.x * 8;
  const int lane = threadIdx.x;

  float srcv[8][4];  // wave-uniform addresses -> scalar loads
#pragma unroll
  for (int r = 0; r < 8; ++r)
#pragma unroll
    for (int q = 0; q < 4; ++q)
      srcv[r][q] = src_s[(k * HH + q) * NN + r0 + r];

  float lacc[8][4], c0a[8][4], c1a[8][4];
#pragma unroll
  for (int r = 0; r < 8; ++r)
#pragma unroll
    for (int q = 0; q < 4; ++q) {
      lacc[r][q] = 0.0f;
      c0a[r][q] = 0.0f;
      c1a[r][q] = 0.0f;
    }

  const float* adjk = adj + (size_t)k * NN * NN;
  const int jb0 = chunk * JCHUNK + lane * 4;

#pragma unroll
  for (int it = 0; it < JCHUNK / 256; ++it) {  // 4 iterations
    const int jb = jb0 + it * 256;
    vf4 ar[8];
#pragma unroll
    for (int r = 0; r < 8; ++r)
      ar[r] = __builtin_nontemporal_load(
          (const vf4*)(adjk + (size_t)(r0 + r) * NN + jb));
#pragma unroll
    for (int h = 0; h < 4; ++h) {
      const size_t pb = (size_t)(k * HH + h) * NN + jb;
      vf4 dv = *(const vf4*)(att_d + pb);
      vf4 g0v = *(const vf4*)(att_g0 + pb);
      vf4 g1v = *(const vf4*)(att_g1 + pb);
#pragma unroll
      for (int jj = 0; jj < 4; ++jj) {
        const float d = dv[jj];
        const float g0 = g0v[jj];
        const float g1 = g1v[jj];
#pragma unroll
        for (int r = 0; r < 8; ++r) {
          float s = srcv[r][h] + d;
          float sl = fmaxf(s, 0.2f * s);
          float p = ar[r][jj] * fexp2(sl);
          lacc[r][h] += p;
          c0a[r][h] = fmaf(p, g0, c0a[r][h]);
          c1a[r][h] = fmaf(p, g1, c1a[r][h]);
        }
      }
    }
  }

  // butterfly reduce the 96 accumulators across 64 lanes
#pragma unroll
  for (int r = 0; r < 8; ++r)
#pragma unroll
    for (int q = 0; q < 4; ++q) {
      float x0 = lacc[r][q], x1 = c0a[r][q], x2 = c1a[r][q];
#pragma unroll
      for (int off = 32; off > 0; off >>= 1) {
        x0 += __shfl_xor(x0, off, 64);
        x1 += __shfl_xor(x1, off, 64);
        x2 += __shfl_xor(x2, off, 64);
      }
      lacc[r][q] = x0;
      c0a[r][q] = x1;
      c1a[r][q] = x2;
    }

  if (lane == 0) {
#pragma unroll
    for (int r = 0; r < 8; ++r)
#pragma unroll
      for (int q = 0; q < 4; ++q) {
        // P layout: [k][chunk][q][{l,a0,a1}][i]
        size_t base =
            (((size_t)(k * JSPLIT + chunk) * HH + q) * 3) * NU + (r0 + r);
        P[base] = lacc[r][q];
        P[base + NU] = c0a[r][q];
        P[base + 2 * (size_t)NU] = c1a[r][q];
      }
  }
}

// ---------------------------------------------------------------------------
// Phase 3: combine chunk partials, divide, mean heads, sum kinds, +bias,
// log_softmax over C=2.
// ---------------------------------------------------------------------------
__global__ __launch_bounds__(256) void gat_phase3(
    const float* __restrict__ P, const float* __restrict__ fc_b,
    float* __restrict__ out) {
  const int i = blockIdx.x * 256 + threadIdx.x;
  if (i >= NU) return;
  float l0 = fc_b[0], l1 = fc_b[1];
#pragma unroll
  for (int k = 0; k < KK; ++k) {
#pragma unroll
    for (int q = 0; q < HH; ++q) {
      float ls = 0.0f, a0 = 0.0f, a1 = 0.0f;
#pragma unroll
      for (int ch = 0; ch < JSPLIT; ++ch) {
        size_t b = (((size_t)(k * JSPLIT + ch) * HH + q) * 3) * NU + i;
        ls += P[b];
        a0 += P[b + NU];
        a1 += P[b + 2 * (size_t)NU];
      }
      float inv = 1.0f / ls;
      l0 = fmaf(0.25f * a0, inv, l0);
      l1 = fmaf(0.25f * a1, inv, l1);
    }
  }
  float m = fmaxf(l0, l1);
  float lse = m + logf(expf(l0 - m) + expf(l1 - m));
  out[i * CC + 0] = l0 - lse;
  out[i * CC + 1] = l1 - lse;
}

extern "C" void kernel_launch(void* const* d_in, const int* in_sizes, int n_in,
                              void* d_out, int out_size, void* d_ws, size_t ws_size,
                              hipStream_t stream) {
  const float* hsrc  = (const float*)d_in[0];  // (1,4096,64)
  const float* hadj  = (const float*)d_in[1];  // (2,1,4096,4096)
  const float* w     = (const float*)d_in[2];  // (2,4,64,64)
  const float* a_src = (const float*)d_in[3];  // (2,4,64,1)
  const float* a_dst = (const float*)d_in[4];  // (2,4,64,1)
  const float* fc_w  = (const float*)d_in[5];  // (2,128)
  const float* fc_b  = (const float*)d_in[6];  // (2,)
  float* out = (float*)d_out;                  // (1,4000,2) fp32

  char* ws = (char*)d_ws;
  float* src_s  = (float*)(ws + 0 * 131072);   // K*H*N floats (128 KB)
  float* att_d  = (float*)(ws + 1 * 131072);
  float* att_g0 = (float*)(ws + 2 * 131072);
  float* att_g1 = (float*)(ws + 3 * 131072);
  float* P      = (float*)(ws + 4 * 131072);   // K*JSPLIT*H*3*NU (1.5 MB)

  dim3 g1(NN / 64, KK * HH);
  gat_phase1<<<g1, 256, 0, stream>>>(hsrc, w, a_src, a_dst, fc_w,
                                     src_s, att_d, att_g0, att_g1);
  dim3 g2(NU / 8, KK * JSPLIT);
  gat_phase2<<<g2, 64, 0, stream>>>(hadj, src_s, att_d, att_g0, att_g1, P);
  gat_phase3<<<(NU + 255) / 256, 256, 0, stream>>>(P, fc_b, out);
}

// Round 5
// 265.216 us; speedup vs baseline: 1.7699x; 1.7699x over previous
//
#include <hip/hip_runtime.h>
#include <math.h>

constexpr int KK = 2;
constexpr int HH = 4;
constexpr int NN = 4096;
constexpr int DD = 64;
constexpr int OO = 64;
constexpr int NU = 4000;
constexpr int CC = 2;
constexpr int JSPLIT = 4;
constexpr int JCHUNK = NN / JSPLIT;  // 1024
constexpr float LOG2E = 1.44269504088896340736f;

typedef float vf4 __attribute__((ext_vector_type(4)));

__device__ __forceinline__ float fexp2(float x) {
#if __has_builtin(__builtin_amdgcn_exp2f)
  return __builtin_amdgcn_exp2f(x);
#else
  return exp2f(x);
#endif
}
__device__ __forceinline__ float frcp(float x) {
#if __has_builtin(__builtin_amdgcn_rcpf)
  return __builtin_amdgcn_rcpf(x);
#else
  return 1.0f / x;
#endif
}
__device__ __forceinline__ float ftanh(float x) {
  float e = fexp2(x * (2.0f * LOG2E));
  return 1.0f - 2.0f * frcp(e + 1.0f);
}

// ---------------------------------------------------------------------------
// Phase 1: per (k,h): hp = h @ w (4096x64 @ 64x64); per node j:
//   src_s[kh][j] = (tanh(hp_j).a_src)*log2e
//   att_d [kh][j] = (tanh(hp_j).a_dst)*log2e
//   att_g0[kh][j] = hp_j . fc_w[0, k*O:], att_g1 likewise  (SoA planes)
// grid (64, K*H), block 256. Thread = 4 rows x 4 o outer-product tile.
// ---------------------------------------------------------------------------
__global__ __launch_bounds__(256) void gat_phase1(
    const float* __restrict__ hsrc, const float* __restrict__ w,
    const float* __restrict__ a_src, const float* __restrict__ a_dst,
    const float* __restrict__ fc_w,
    float* __restrict__ src_s, float* __restrict__ att_d,
    float* __restrict__ att_g0, float* __restrict__ att_g1) {
  const int kh = blockIdx.y;  // 0..7
  const int k = kh >> 2;
  const int i0 = blockIdx.x * 64;
  const int tid = threadIdx.x;

  __shared__ float h_s[DD][68];
  __shared__ float w_s[DD][OO];

  {
    const float4* wp = (const float4*)(w + (size_t)kh * DD * OO);
    float4* ws4 = (float4*)w_s;
    for (int t = tid; t < DD * OO / 4; t += 256) ws4[t] = wp[t];
  }
  for (int t = tid; t < 1024; t += 256) {
    const int row = t >> 4;
    const int f4 = (t & 15) * 4;
    float4 v = *(const float4*)(hsrc + (size_t)(i0 + row) * DD + f4);
    h_s[f4 + 0][row] = v.x;
    h_s[f4 + 1][row] = v.y;
    h_s[f4 + 2][row] = v.z;
    h_s[f4 + 3][row] = v.w;
  }
  __syncthreads();

  const int og = tid & 15;
  const int rg = tid >> 4;
  const int o0 = og * 4;
  const int r0 = rg * 4;

  float hp[4][4];
#pragma unroll
  for (int j = 0; j < 4; ++j)
#pragma unroll
    for (int u = 0; u < 4; ++u) hp[j][u] = 0.0f;

#pragma unroll 8
  for (int f = 0; f < DD; ++f) {
    float4 hv = *(const float4*)&h_s[f][r0];
    float4 wv = *(const float4*)&w_s[f][o0];
    hp[0][0] = fmaf(hv.x, wv.x, hp[0][0]);
    hp[0][1] = fmaf(hv.x, wv.y, hp[0][1]);
    hp[0][2] = fmaf(hv.x, wv.z, hp[0][2]);
    hp[0][3] = fmaf(hv.x, wv.w, hp[0][3]);
    hp[1][0] = fmaf(hv.y, wv.x, hp[1][0]);
    hp[1][1] = fmaf(hv.y, wv.y, hp[1][1]);
    hp[1][2] = fmaf(hv.y, wv.z, hp[1][2]);
    hp[1][3] = fmaf(hv.y, wv.w, hp[1][3]);
    hp[2][0] = fmaf(hv.z, wv.x, hp[2][0]);
    hp[2][1] = fmaf(hv.z, wv.y, hp[2][1]);
    hp[2][2] = fmaf(hv.z, wv.z, hp[2][2]);
    hp[2][3] = fmaf(hv.z, wv.w, hp[2][3]);
    hp[3][0] = fmaf(hv.w, wv.x, hp[3][0]);
    hp[3][1] = fmaf(hv.w, wv.y, hp[3][1]);
    hp[3][2] = fmaf(hv.w, wv.z, hp[3][2]);
    hp[3][3] = fmaf(hv.w, wv.w, hp[3][3]);
  }

  float as[4], ad[4], f0[4], f1[4];
#pragma unroll
  for (int u = 0; u < 4; ++u) {
    as[u] = a_src[kh * OO + o0 + u];
    ad[u] = a_dst[kh * OO + o0 + u];
    f0[u] = fc_w[0 * (KK * OO) + k * OO + o0 + u];
    f1[u] = fc_w[1 * (KK * OO) + k * OO + o0 + u];
  }

#pragma unroll
  for (int j = 0; j < 4; ++j) {
    float sp = 0.0f, dp = 0.0f, g0 = 0.0f, g1 = 0.0f;
#pragma unroll
    for (int u = 0; u < 4; ++u) {
      float v = hp[j][u];
      float t = ftanh(v);
      sp = fmaf(t, as[u], sp);
      dp = fmaf(t, ad[u], dp);
      g0 = fmaf(v, f0[u], g0);
      g1 = fmaf(v, f1[u], g1);
    }
#pragma unroll
    for (int off = 1; off < 16; off <<= 1) {
      sp += __shfl_xor(sp, off, 64);
      dp += __shfl_xor(dp, off, 64);
      g0 += __shfl_xor(g0, off, 64);
      g1 += __shfl_xor(g1, off, 64);
    }
    if (og == 0) {
      const int i = i0 + r0 + j;
      src_s[kh * NN + i] = sp * LOG2E;
      att_d[kh * NN + i] = dp * LOG2E;
      att_g0[kh * NN + i] = g0;
      att_g1[kh * NN + i] = g1;
    }
  }
}

// ---------------------------------------------------------------------------
// Phase 2: partial softmax sums over a 1024-j chunk, 16 rows per block.
// grid (NU/16, K*JSPLIT), block 256 = 4 waves. Lane = (jsub<<4) | row:
// 16 rows x 4 j-subs; each lane owns 12 accumulators (4 heads x {l,a0,a1}).
// Wave w handles 16-j tiles t = w, w+4, ... Adjacency load: 16 rows x 16B
// = 16 full cache lines per instruction (100% line utilization).
//   p = adj * exp2(leaky(src'+dst')); l += p; a_c += p*g_c
// Reduction: butterfly xor 16,32 (j-subs) + LDS combine across 4 waves.
// ---------------------------------------------------------------------------
__global__ __launch_bounds__(256) void gat_phase2(
    const float* __restrict__ adj, const float* __restrict__ src_s,
    const float* __restrict__ att_d, const float* __restrict__ att_g0,
    const float* __restrict__ att_g1, float* __restrict__ P) {
  const int k = blockIdx.y >> 2;
  const int chunk = blockIdx.y & 3;
  const int r0 = blockIdx.x * 16;
  const int tid = threadIdx.x;
  const int wave = tid >> 6;
  const int lane = tid & 63;
  const int row = lane & 15;
  const int jsub = lane >> 4;
  const int i = r0 + row;

  float sreg[4];
#pragma unroll
  for (int h = 0; h < 4; ++h) sreg[h] = src_s[(k * HH + h) * NN + i];

  float l[4], a0[4], a1[4];
#pragma unroll
  for (int h = 0; h < 4; ++h) {
    l[h] = 0.0f;
    a0[h] = 0.0f;
    a1[h] = 0.0f;
  }

  const float* adjrow = adj + (size_t)k * NN * NN + (size_t)i * NN;
  const int jbase = chunk * JCHUNK + jsub * 4;

#pragma unroll 2
  for (int t = wave; t < JCHUNK / 16; t += 4) {  // 16 tiles per wave
    const int jb = jbase + t * 16;
    vf4 av = *(const vf4*)(adjrow + jb);
#pragma unroll
    for (int h = 0; h < 4; ++h) {
      const size_t pb = (size_t)(k * HH + h) * NN + jb;
      vf4 dv = *(const vf4*)(att_d + pb);
      vf4 g0v = *(const vf4*)(att_g0 + pb);
      vf4 g1v = *(const vf4*)(att_g1 + pb);
#pragma unroll
      for (int jj = 0; jj < 4; ++jj) {
        float s = sreg[h] + dv[jj];
        float sl = fmaxf(s, 0.2f * s);
        float p = av[jj] * fexp2(sl);
        l[h] += p;
        a0[h] = fmaf(p, g0v[jj], a0[h]);
        a1[h] = fmaf(p, g1v[jj], a1[h]);
      }
    }
  }

  // reduce across the 4 j-sub lane groups (lane bits 4,5)
#pragma unroll
  for (int h = 0; h < 4; ++h) {
    l[h] += __shfl_xor(l[h], 16, 64);
    l[h] += __shfl_xor(l[h], 32, 64);
    a0[h] += __shfl_xor(a0[h], 16, 64);
    a0[h] += __shfl_xor(a0[h], 32, 64);
    a1[h] += __shfl_xor(a1[h], 16, 64);
    a1[h] += __shfl_xor(a1[h], 32, 64);
  }

  // cross-wave combine: sred[wave][v][row], v = h*3+c
  __shared__ float sred[4][12][16];
  if (lane < 16) {
#pragma unroll
    for (int h = 0; h < 4; ++h) {
      sred[wave][h * 3 + 0][row] = l[h];
      sred[wave][h * 3 + 1][row] = a0[h];
      sred[wave][h * 3 + 2][row] = a1[h];
    }
  }
  __syncthreads();
  if (tid < 192) {
    const int v = tid >> 4;   // 0..11 = h*3+c
    const int rr = tid & 15;
    float sum = sred[0][v][rr] + sred[1][v][rr] + sred[2][v][rr] + sred[3][v][rr];
    const int h = v / 3, c = v % 3;
    // P layout: [k][chunk][h][{l,a0,a1}][i]
    size_t base = ((((size_t)(k * JSPLIT + chunk) * HH + h) * 3 + c)) * NU + (r0 + rr);
    P[base] = sum;
  }
}

// ---------------------------------------------------------------------------
// Phase 3: combine chunk partials, divide, mean heads, sum kinds, +bias,
// log_softmax over C=2.
// ---------------------------------------------------------------------------
__global__ __launch_bounds__(256) void gat_phase3(
    const float* __restrict__ P, const float* __restrict__ fc_b,
    float* __restrict__ out) {
  const int i = blockIdx.x * 256 + threadIdx.x;
  if (i >= NU) return;
  float l0 = fc_b[0], l1 = fc_b[1];
#pragma unroll
  for (int k = 0; k < KK; ++k) {
#pragma unroll
    for (int q = 0; q < HH; ++q) {
      float ls = 0.0f, a0 = 0.0f, a1 = 0.0f;
#pragma unroll
      for (int ch = 0; ch < JSPLIT; ++ch) {
        size_t b = (((size_t)(k * JSPLIT + ch) * HH + q) * 3) * NU + i;
        ls += P[b];
        a0 += P[b + NU];
        a1 += P[b + 2 * (size_t)NU];
      }
      float inv = 1.0f / ls;
      l0 = fmaf(0.25f * a0, inv, l0);
      l1 = fmaf(0.25f * a1, inv, l1);
    }
  }
  float m = fmaxf(l0, l1);
  float lse = m + logf(expf(l0 - m) + expf(l1 - m));
  out[i * CC + 0] = l0 - lse;
  out[i * CC + 1] = l1 - lse;
}

extern "C" void kernel_launch(void* const* d_in, const int* in_sizes, int n_in,
                              void* d_out, int out_size, void* d_ws, size_t ws_size,
                              hipStream_t stream) {
  const float* hsrc  = (const float*)d_in[0];  // (1,4096,64)
  const float* hadj  = (const float*)d_in[1];  // (2,1,4096,4096)
  const float* w     = (const float*)d_in[2];  // (2,4,64,64)
  const float* a_src = (const float*)d_in[3];  // (2,4,64,1)
  const float* a_dst = (const float*)d_in[4];  // (2,4,64,1)
  const float* fc_w  = (const float*)d_in[5];  // (2,128)
  const float* fc_b  = (const float*)d_in[6];  // (2,)
  float* out = (float*)d_out;                  // (1,4000,2) fp32

  char* ws = (char*)d_ws;
  float* src_s  = (float*)(ws + 0 * 131072);   // K*H*N floats (128 KB)
  float* att_d  = (float*)(ws + 1 * 131072);
  float* att_g0 = (float*)(ws + 2 * 131072);
  float* att_g1 = (float*)(ws + 3 * 131072);
  float* P      = (float*)(ws + 4 * 131072);   // K*JSPLIT*H*3*NU (1.5 MB)

  dim3 g1(NN / 64, KK * HH);
  gat_phase1<<<g1, 256, 0, stream>>>(hsrc, w, a_src, a_dst, fc_w,
                                     src_s, att_d, att_g0, att_g1);
  dim3 g2(NU / 16, KK * JSPLIT);
  gat_phase2<<<g2, 256, 0, stream>>>(hadj, src_s, att_d, att_g0, att_g1, P);
  gat_phase3<<<(NU + 255) / 256, 256, 0, stream>>>(P, fc_b, out);
}

// Round 6
// 222.747 us; speedup vs baseline: 2.1073x; 1.1907x over previous
//
#include <hip/hip_runtime.h>
#include <math.h>

constexpr int KK = 2;
constexpr int HH = 4;
constexpr int NN = 4096;
constexpr int DD = 64;
constexpr int OO = 64;
constexpr int NU = 4000;
constexpr int CC = 2;
constexpr int JSPLIT = 8;
constexpr int JCHUNK = NN / JSPLIT;        // 512
constexpr int NTILE = JCHUNK / 16;         // 32 tiles of 16 j
constexpr float LOG2E = 1.44269504088896340736f;

typedef float vf4 __attribute__((ext_vector_type(4)));

__device__ __forceinline__ float fexp2(float x) {
#if __has_builtin(__builtin_amdgcn_exp2f)
  return __builtin_amdgcn_exp2f(x);
#else
  return exp2f(x);
#endif
}
__device__ __forceinline__ float frcp(float x) {
#if __has_builtin(__builtin_amdgcn_rcpf)
  return __builtin_amdgcn_rcpf(x);
#else
  return 1.0f / x;
#endif
}
__device__ __forceinline__ float ftanh(float x) {
  float e = fexp2(x * (2.0f * LOG2E));
  return 1.0f - 2.0f * frcp(e + 1.0f);
}

// ---------------------------------------------------------------------------
// Phase 1: per (k,h): hp = h @ w (4096x64 @ 64x64); per node j:
//   src_s[kh][j] = (tanh(hp_j).a_src)*log2e
//   att_d [kh][j] = (tanh(hp_j).a_dst)*log2e
//   att_g0[kh][j] = hp_j . fc_w[0, k*O:], att_g1 likewise  (SoA planes)
// ---------------------------------------------------------------------------
__global__ __launch_bounds__(256) void gat_phase1(
    const float* __restrict__ hsrc, const float* __restrict__ w,
    const float* __restrict__ a_src, const float* __restrict__ a_dst,
    const float* __restrict__ fc_w,
    float* __restrict__ src_s, float* __restrict__ att_d,
    float* __restrict__ att_g0, float* __restrict__ att_g1) {
  const int kh = blockIdx.y;  // 0..7
  const int k = kh >> 2;
  const int i0 = blockIdx.x * 64;
  const int tid = threadIdx.x;

  __shared__ float h_s[DD][68];
  __shared__ float w_s[DD][OO];

  {
    const float4* wp = (const float4*)(w + (size_t)kh * DD * OO);
    float4* ws4 = (float4*)w_s;
    for (int t = tid; t < DD * OO / 4; t += 256) ws4[t] = wp[t];
  }
  for (int t = tid; t < 1024; t += 256) {
    const int row = t >> 4;
    const int f4 = (t & 15) * 4;
    float4 v = *(const float4*)(hsrc + (size_t)(i0 + row) * DD + f4);
    h_s[f4 + 0][row] = v.x;
    h_s[f4 + 1][row] = v.y;
    h_s[f4 + 2][row] = v.z;
    h_s[f4 + 3][row] = v.w;
  }
  __syncthreads();

  const int og = tid & 15;
  const int rg = tid >> 4;
  const int o0 = og * 4;
  const int r0 = rg * 4;

  float hp[4][4];
#pragma unroll
  for (int j = 0; j < 4; ++j)
#pragma unroll
    for (int u = 0; u < 4; ++u) hp[j][u] = 0.0f;

#pragma unroll 8
  for (int f = 0; f < DD; ++f) {
    float4 hv = *(const float4*)&h_s[f][r0];
    float4 wv = *(const float4*)&w_s[f][o0];
    hp[0][0] = fmaf(hv.x, wv.x, hp[0][0]);
    hp[0][1] = fmaf(hv.x, wv.y, hp[0][1]);
    hp[0][2] = fmaf(hv.x, wv.z, hp[0][2]);
    hp[0][3] = fmaf(hv.x, wv.w, hp[0][3]);
    hp[1][0] = fmaf(hv.y, wv.x, hp[1][0]);
    hp[1][1] = fmaf(hv.y, wv.y, hp[1][1]);
    hp[1][2] = fmaf(hv.y, wv.z, hp[1][2]);
    hp[1][3] = fmaf(hv.y, wv.w, hp[1][3]);
    hp[2][0] = fmaf(hv.z, wv.x, hp[2][0]);
    hp[2][1] = fmaf(hv.z, wv.y, hp[2][1]);
    hp[2][2] = fmaf(hv.z, wv.z, hp[2][2]);
    hp[2][3] = fmaf(hv.z, wv.w, hp[2][3]);
    hp[3][0] = fmaf(hv.w, wv.x, hp[3][0]);
    hp[3][1] = fmaf(hv.w, wv.y, hp[3][1]);
    hp[3][2] = fmaf(hv.w, wv.z, hp[3][2]);
    hp[3][3] = fmaf(hv.w, wv.w, hp[3][3]);
  }

  float as[4], ad[4], f0[4], f1[4];
#pragma unroll
  for (int u = 0; u < 4; ++u) {
    as[u] = a_src[kh * OO + o0 + u];
    ad[u] = a_dst[kh * OO + o0 + u];
    f0[u] = fc_w[0 * (KK * OO) + k * OO + o0 + u];
    f1[u] = fc_w[1 * (KK * OO) + k * OO + o0 + u];
  }

#pragma unroll
  for (int j = 0; j < 4; ++j) {
    float sp = 0.0f, dp = 0.0f, g0 = 0.0f, g1 = 0.0f;
#pragma unroll
    for (int u = 0; u < 4; ++u) {
      float v = hp[j][u];
      float t = ftanh(v);
      sp = fmaf(t, as[u], sp);
      dp = fmaf(t, ad[u], dp);
      g0 = fmaf(v, f0[u], g0);
      g1 = fmaf(v, f1[u], g1);
    }
#pragma unroll
    for (int off = 1; off < 16; off <<= 1) {
      sp += __shfl_xor(sp, off, 64);
      dp += __shfl_xor(dp, off, 64);
      g0 += __shfl_xor(g0, off, 64);
      g1 += __shfl_xor(g1, off, 64);
    }
    if (og == 0) {
      const int i = i0 + r0 + j;
      src_s[kh * NN + i] = sp * LOG2E;
      att_d[kh * NN + i] = dp * LOG2E;
      att_g0[kh * NN + i] = g0;
      att_g1[kh * NN + i] = g1;
    }
  }
}

// ---------------------------------------------------------------------------
// Phase 2: partial softmax sums over a 512-j chunk, 16 rows per block.
// grid (NU/16, K*JSPLIT), block 256 = 4 waves. Lane = (jsub<<4) | row.
// Block stages the chunk's att planes (12 x 512 floats = 24 KB) into LDS
// once; inner loop per 16-j tile: 1 dense global adj b128 (prefetched 2
// tiles ahead) + 12 broadcast ds_read_b128 + VALU.
//   p = adj * exp2(leaky(src'+dst')); l += p; a_c += p*g_c
// Reduction: butterfly xor 16,32 (j-subs) + LDS combine across 4 waves.
// ---------------------------------------------------------------------------
__global__ __launch_bounds__(256) void gat_phase2(
    const float* __restrict__ adj, const float* __restrict__ src_s,
    const float* __restrict__ att_d, const float* __restrict__ att_g0,
    const float* __restrict__ att_g1, float* __restrict__ P) {
  const int k = blockIdx.y >> 3;
  const int chunk = blockIdx.y & 7;
  const int r0 = blockIdx.x * 16;
  const int tid = threadIdx.x;
  const int wave = tid >> 6;
  const int lane = tid & 63;
  const int row = lane & 15;
  const int jsub = lane >> 4;
  const int i = r0 + row;
  const int j0 = chunk * JCHUNK;

  // ---- stage att chunk into LDS: lds_att[v][j], v = plane*4 + h ----
  __shared__ float lds_att[12][JCHUNK];
  {
    const float* planes[3] = {att_d, att_g0, att_g1};
#pragma unroll
    for (int step = 0; step < 6; ++step) {  // 1536 vf4 total / 256 thr
      const int fi = step * 256 + tid;
      const int v = fi >> 7;            // 128 vf4 per (plane,h) row
      const int pos = (fi & 127) * 4;
      const int p = v >> 2, h = v & 3;
      vf4 val = *(const vf4*)(planes[p] + (size_t)(k * HH + h) * NN + j0 + pos);
      *(vf4*)&lds_att[v][pos] = val;
    }
  }

  float sreg[4];
#pragma unroll
  for (int h = 0; h < 4; ++h) sreg[h] = src_s[(k * HH + h) * NN + i];

  float l[4], a0[4], a1[4];
#pragma unroll
  for (int h = 0; h < 4; ++h) {
    l[h] = 0.0f;
    a0[h] = 0.0f;
    a1[h] = 0.0f;
  }

  __syncthreads();

  // wave handles tiles t = wave, wave+4, ..., 8 of them; adj prefetch x2
  const float* arow = adj + (size_t)k * NN * NN + (size_t)i * NN + j0 + jsub * 4;
  vf4 apre0 = *(const vf4*)(arow + (wave + 0) * 16);
  vf4 apre1 = *(const vf4*)(arow + (wave + 4) * 16);

#pragma unroll
  for (int s = 0; s < 8; ++s) {
    const int t = wave + s * 4;
    const vf4 av = apre0;
    apre0 = apre1;
    if (s < 6) apre1 = *(const vf4*)(arow + (t + 8) * 16);
    const int jloc = jsub * 4 + t * 16;
#pragma unroll
    for (int h = 0; h < 4; ++h) {
      vf4 dv = *(const vf4*)&lds_att[0 * 4 + h][jloc];
      vf4 g0v = *(const vf4*)&lds_att[1 * 4 + h][jloc];
      vf4 g1v = *(const vf4*)&lds_att[2 * 4 + h][jloc];
#pragma unroll
      for (int jj = 0; jj < 4; ++jj) {
        float s2 = sreg[h] + dv[jj];
        float sl = fmaxf(s2, 0.2f * s2);
        float p = av[jj] * fexp2(sl);
        l[h] += p;
        a0[h] = fmaf(p, g0v[jj], a0[h]);
        a1[h] = fmaf(p, g1v[jj], a1[h]);
      }
    }
  }

  // reduce across the 4 j-sub lane groups (lane bits 4,5)
#pragma unroll
  for (int h = 0; h < 4; ++h) {
    l[h] += __shfl_xor(l[h], 16, 64);
    l[h] += __shfl_xor(l[h], 32, 64);
    a0[h] += __shfl_xor(a0[h], 16, 64);
    a0[h] += __shfl_xor(a0[h], 32, 64);
    a1[h] += __shfl_xor(a1[h], 16, 64);
    a1[h] += __shfl_xor(a1[h], 32, 64);
  }

  // cross-wave combine: sred[wave][v][row], v = h*3+c
  __shared__ float sred[4][12][16];
  if (lane < 16) {
#pragma unroll
    for (int h = 0; h < 4; ++h) {
      sred[wave][h * 3 + 0][row] = l[h];
      sred[wave][h * 3 + 1][row] = a0[h];
      sred[wave][h * 3 + 2][row] = a1[h];
    }
  }
  __syncthreads();
  if (tid < 192) {
    const int v = tid >> 4;  // 0..11 = h*3+c
    const int rr = tid & 15;
    float sum =
        sred[0][v][rr] + sred[1][v][rr] + sred[2][v][rr] + sred[3][v][rr];
    const int h = v / 3, c = v % 3;
    // P layout: [k][chunk][h][{l,a0,a1}][i]
    size_t base =
        ((((size_t)(k * JSPLIT + chunk) * HH + h) * 3 + c)) * NU + (r0 + rr);
    P[base] = sum;
  }
}

// ---------------------------------------------------------------------------
// Phase 3: combine chunk partials, divide, mean heads, sum kinds, +bias,
// log_softmax over C=2.
// ---------------------------------------------------------------------------
__global__ __launch_bounds__(256) void gat_phase3(
    const float* __restrict__ P, const float* __restrict__ fc_b,
    float* __restrict__ out) {
  const int i = blockIdx.x * 256 + threadIdx.x;
  if (i >= NU) return;
  float l0 = fc_b[0], l1 = fc_b[1];
#pragma unroll
  for (int k = 0; k < KK; ++k) {
#pragma unroll
    for (int q = 0; q < HH; ++q) {
      float ls = 0.0f, a0 = 0.0f, a1 = 0.0f;
#pragma unroll
      for (int ch = 0; ch < JSPLIT; ++ch) {
        size_t b = (((size_t)(k * JSPLIT + ch) * HH + q) * 3) * NU + i;
        ls += P[b];
        a0 += P[b + NU];
        a1 += P[b + 2 * (size_t)NU];
      }
      float inv = 1.0f / ls;
      l0 = fmaf(0.25f * a0, inv, l0);
      l1 = fmaf(0.25f * a1, inv, l1);
    }
  }
  float m = fmaxf(l0, l1);
  float lse = m + logf(expf(l0 - m) + expf(l1 - m));
  out[i * CC + 0] = l0 - lse;
  out[i * CC + 1] = l1 - lse;
}

extern "C" void kernel_launch(void* const* d_in, const int* in_sizes, int n_in,
                              void* d_out, int out_size, void* d_ws, size_t ws_size,
                              hipStream_t stream) {
  const float* hsrc  = (const float*)d_in[0];  // (1,4096,64)
  const float* hadj  = (const float*)d_in[1];  // (2,1,4096,4096)
  const float* w     = (const float*)d_in[2];  // (2,4,64,64)
  const float* a_src = (const float*)d_in[3];  // (2,4,64,1)
  const float* a_dst = (const float*)d_in[4];  // (2,4,64,1)
  const float* fc_w  = (const float*)d_in[5];  // (2,128)
  const float* fc_b  = (const float*)d_in[6];  // (2,)
  float* out = (float*)d_out;                  // (1,4000,2) fp32

  char* ws = (char*)d_ws;
  float* src_s  = (float*)(ws + 0 * 131072);   // K*H*N floats (128 KB each)
  float* att_d  = (float*)(ws + 1 * 131072);
  float* att_g0 = (float*)(ws + 2 * 131072);
  float* att_g1 = (float*)(ws + 3 * 131072);
  float* P      = (float*)(ws + 4 * 131072);   // K*JSPLIT*H*3*NU = 3 MB

  dim3 g1(NN / 64, KK * HH);
  gat_phase1<<<g1, 256, 0, stream>>>(hsrc, w, a_src, a_dst, fc_w,
                                     src_s, att_d, att_g0, att_g1);
  dim3 g2(NU / 16, KK * JSPLIT);
  gat_phase2<<<g2, 256, 0, stream>>>(hadj, src_s, att_d, att_g0, att_g1, P);
  gat_phase3<<<(NU + 255) / 256, 256, 0, stream>>>(P, fc_b, out);
}